// Round 1
// baseline (122962.085 us; speedup 1.0000x reference)
//
#include <hip/hip_runtime.h>
#include <math.h>

#define BB 32
#define T_INN 256
#define T_OUTT 512
#define N_MELL 80
#define E_DIMM 512
#define A_RNNN 1024
#define PRENETT 256
#define A_DIMM 128
#define N_FILTT 32

// ---- workspace offsets (floats) ----
#define OFF_X2   0u           // 512*32*256
#define OFF_PM   4194304u     // 32*256*128
#define OFF_AH   5242880u     // 2 * 32*1024
#define OFF_AC   5308416u     // 32*1024
#define OFF_DH   5341184u     // 2 * 32*1024
#define OFF_DC   5406720u     // 32*1024
#define OFF_CTX  5439488u     // 32*512
#define OFF_AWC  5455872u     // 32*256
#define WS_TOTAL 5464064u

// ---- output offsets (floats) ----
#define OUT_MEL   0u
#define OUT_GATE  1310720u
#define OUT_ALIGN 1327104u

__device__ __forceinline__ float sigf(float x) { return 1.f / (1.f + expf(-x)); }

// ============================================================
// Prenet for all timesteps: x2[t][b][q], t-group of 16 per block
// ============================================================
__global__ __launch_bounds__(256) void prenet_kernel(
    const float* __restrict__ dec_in,   // (B, 80, 512)
    const float* __restrict__ w1,       // (256, 80)
    const float* __restrict__ w2,       // (256, 256)
    float* __restrict__ x2)             // (512, 32, 256)
{
    int b  = blockIdx.x & 31;
    int t0 = (blockIdx.x >> 5) * 16;
    __shared__ float xin[16][80];
    __shared__ float h1[16][257];

    for (int i = threadIdx.x; i < 16 * 80; i += 256) {
        int tt = i / 80, m = i - tt * 80;
        int t = t0 + tt;
        xin[tt][m] = (t == 0) ? 0.f
                   : dec_in[(size_t)b * 80 * 512 + (size_t)m * 512 + (t - 1)];
    }
    __syncthreads();
    for (int i = threadIdx.x; i < 16 * 256; i += 256) {
        int tt = i >> 8, p = i & 255;
        const float* wr = w1 + p * 80;
        float s = 0.f;
        for (int m = 0; m < 80; ++m) s += xin[tt][m] * wr[m];
        h1[tt][p] = fmaxf(s, 0.f);
    }
    __syncthreads();
    for (int i = threadIdx.x; i < 16 * 256; i += 256) {
        int tt = i >> 8, q = i & 255;
        const float* wr = w2 + q * 256;
        float s = 0.f;
        for (int p = 0; p < 256; ++p) s += h1[tt][p] * wr[p];
        int t = t0 + tt;
        x2[(size_t)t * (32 * 256) + b * 256 + q] = fmaxf(s, 0.f);
    }
}

// ============================================================
// processed_memory[b][tt][d] = memory[b][tt][:] . wm[d][:]
// ============================================================
__global__ __launch_bounds__(128) void pm_kernel(
    const float* __restrict__ memory,   // (32, 256, 512)
    const float* __restrict__ wm,       // (128, 512)
    float* __restrict__ pm)             // (32, 256, 128)
{
    int b = blockIdx.y, tt0 = blockIdx.x * 16;
    __shared__ float ms[16][513];
    for (int i = threadIdx.x; i < 16 * 512; i += 128) {
        int tt = i >> 9, e = i & 511;
        ms[tt][e] = memory[(size_t)b * 131072 + (size_t)(tt0 + tt) * 512 + e];
    }
    __syncthreads();
    int d = threadIdx.x;
    float acc[16];
#pragma unroll
    for (int i = 0; i < 16; ++i) acc[i] = 0.f;
    const float* wr = wm + d * 512;
    for (int e = 0; e < 512; ++e) {
        float w = wr[e];
#pragma unroll
        for (int ttl = 0; ttl < 16; ++ttl) acc[ttl] += w * ms[ttl][e];
    }
    for (int ttl = 0; ttl < 16; ++ttl)
        pm[(size_t)b * 32768 + (size_t)(tt0 + ttl) * 128 + d] = acc[ttl];
}

// ============================================================
// Fused LSTM: gates GEMM (rows = 4 gates x 4 j per block, all 32 b)
// input = [seg0 | seg1 | seg2] per b.  Weights: wih (Kih cols) then whh.
// ============================================================
__global__ __launch_bounds__(256) void lstm_kernel(
    const float* __restrict__ seg0, int s0len, int s0str,
    const float* __restrict__ seg1, int s1len, int s1str,
    const float* __restrict__ seg2, int s2str,
    const float* __restrict__ wih, int Kih,
    const float* __restrict__ whh,
    const float* __restrict__ bias,
    float* __restrict__ c_state,
    float* __restrict__ h_out,
    int K)
{
    __shared__ float inT[32][68];
    __shared__ float wT[16][68];
    __shared__ float ex[2][4][32];

    int tid = threadIdx.x;
    int jb  = blockIdx.x;              // 0..255, covers j = jb*4 + jl
    int b   = tid & 31;
    int jl  = (tid >> 5) & 3;
    int gh  = tid >> 7;                // 0: gates i,f ; 1: gates g,o

    const float* ir  = &inT[b][0];
    const float* w0r = &wT[gh * 8 + jl][0];
    const float* w1r = &wT[gh * 8 + 4 + jl][0];

    // staging indices
    int sr  = tid >> 4;                // weight row 0..15
    int sf4 = tid & 15;                // float4 index
    int sg  = sr >> 2, sjl = sr & 3;
    int wrow = sg * 1024 + jb * 4 + sjl;
    int Khh = K - Kih;

    float acc0 = 0.f, acc1 = 0.f;

    for (int k0 = 0; k0 < K; k0 += 64) {
        __syncthreads();
        // stage weights: 16 rows x 64
        {
            const float* wp; int wpitch, wcol;
            if (k0 < Kih) { wp = wih; wpitch = Kih; wcol = k0; }
            else          { wp = whh; wpitch = Khh; wcol = k0 - Kih; }
            float4 wv = *(const float4*)(wp + (size_t)wrow * wpitch + wcol + sf4 * 4);
            *(float4*)&wT[sr][sf4 * 4] = wv;
        }
        // stage inputs: 32 b x 64
        {
            const float* sp; int str, off;
            if (k0 < s0len)          { sp = seg0; str = s0str; off = k0; }
            else if (k0 < s0len + s1len) { sp = seg1; str = s1str; off = k0 - s0len; }
            else                     { sp = seg2; str = s2str; off = k0 - s0len - s1len; }
#pragma unroll
            for (int n = 0; n < 2; ++n) {
                int idx = tid + n * 256;
                int lb = idx >> 4, lf = idx & 15;
                float4 v = *(const float4*)(sp + (size_t)lb * str + off + lf * 4);
                *(float4*)&inT[lb][lf * 4] = v;
            }
        }
        __syncthreads();
#pragma unroll
        for (int kk = 0; kk < 64; kk += 4) {
            float4 iv = *(const float4*)&ir[kk];
            float4 a  = *(const float4*)&w0r[kk];
            float4 c  = *(const float4*)&w1r[kk];
            acc0 = fmaf(iv.x, a.x, acc0); acc0 = fmaf(iv.y, a.y, acc0);
            acc0 = fmaf(iv.z, a.z, acc0); acc0 = fmaf(iv.w, a.w, acc0);
            acc1 = fmaf(iv.x, c.x, acc1); acc1 = fmaf(iv.y, c.y, acc1);
            acc1 = fmaf(iv.z, c.z, acc1); acc1 = fmaf(iv.w, c.w, acc1);
        }
    }

    __syncthreads();
    if (gh == 1) { ex[0][jl][b] = acc0; ex[1][jl][b] = acc1; }
    __syncthreads();
    if (gh == 0) {
        int j = jb * 4 + jl;
        float gi = acc0 + bias[j];
        float gf = acc1 + bias[1024 + j];
        float gg = ex[0][jl][b] + bias[2048 + j];
        float go = ex[1][jl][b] + bias[3072 + j];
        float c  = c_state[b * 1024 + j];
        float c2 = sigf(gf) * c + sigf(gi) * tanhf(gg);
        float h2 = sigf(go) * tanhf(c2);
        c_state[b * 1024 + j] = c2;
        h_out[b * 1024 + j]   = h2;
    }
}

// ============================================================
// Attention: one block per batch row, 1024 threads
// ============================================================
__global__ __launch_bounds__(1024) void attn_kernel(
    const float* __restrict__ memory,     // (32,256,512)
    const int*   __restrict__ mlen,
    const float* __restrict__ wq,         // (128,1024)
    const float* __restrict__ v,          // (128)
    const float* __restrict__ loc_conv,   // (32,2,31)
    const float* __restrict__ loc_dense,  // (128,32)
    const float* __restrict__ pm,         // (32,256,128)
    const float* __restrict__ ah,         // current att hidden (32,1024)
    float* __restrict__ ctx,              // (32,512)
    float* __restrict__ awc,              // (32,256)
    float* __restrict__ align_out,        // (32,512,256) region of d_out
    int t)
{
    int b = blockIdx.x, tid = threadIdx.x;
    __shared__ float aw_s[256];
    __shared__ float awc_s[256];
    __shared__ float locT[32][256];
    __shared__ float pq_s[128];
    __shared__ float red[1024];
    __shared__ float wgt_s[256];

    int len = mlen[b];

    if (tid < 256) {
        aw_s[tid]  = (t == 0) ? 0.f
                   : align_out[(size_t)b * 131072 + (size_t)(t - 1) * 256 + tid];
        awc_s[tid] = awc[b * 256 + tid];
    }
    __syncthreads();

    // location conv: loc[f][tt]
    for (int idx = tid; idx < 32 * 256; idx += 1024) {
        int tt = idx & 255, f = idx >> 8;
        const float* kc = loc_conv + f * 62;
        float s = 0.f;
#pragma unroll
        for (int k = 0; k < 31; ++k) {
            int p = tt + k - 15;
            if (p >= 0 && p < 256)
                s += kc[k] * aw_s[p] + kc[31 + k] * awc_s[p];
        }
        locT[f][tt] = s;
    }

    // pq[d] = ah[b] . wq[d]  (8-way split)
    {
        int d = tid >> 3, p = tid & 7;
        const float* wr = wq + (size_t)d * 1024 + p * 128;
        const float* hr = ah + b * 1024 + p * 128;
        float s = 0.f;
        for (int k = 0; k < 128; ++k) s += wr[k] * hr[k];
        red[tid] = s;
    }
    __syncthreads();
    if (tid < 128) {
        float s = 0.f;
#pragma unroll
        for (int p = 0; p < 8; ++p) s += red[tid * 8 + p];
        pq_s[tid] = s;
    }
    __syncthreads();

    // energies: e[tt] = sum_d tanh(pq+loc@ld+pm) * v[d]  (4-way d split)
    {
        int tt = tid & 255, dp = tid >> 8;
        float locf[32];
#pragma unroll
        for (int f = 0; f < 32; ++f) locf[f] = locT[f][tt];
        const float* pmr = pm + (size_t)b * 32768 + (size_t)tt * 128;
        float s = 0.f;
        for (int dl = 0; dl < 32; ++dl) {
            int d = dp * 32 + dl;
            const float* ldr = loc_dense + d * 32;
            float x = pq_s[d] + pmr[d];
#pragma unroll
            for (int f = 0; f < 32; ++f) x += locf[f] * ldr[f];
            s += tanhf(x) * v[d];
        }
        red[dp * 256 + tt] = s;
    }
    __syncthreads();

    float e = 0.f;
    if (tid < 256) {
        e = red[tid] + red[256 + tid] + red[512 + tid] + red[768 + tid];
        if (tid >= len) e = -1e9f;
    }
    __syncthreads();
    if (tid < 256) red[tid] = e; 
    __syncthreads();
    for (int s = 128; s > 0; s >>= 1) {
        if (tid < s) red[tid] = fmaxf(red[tid], red[tid + s]);
        __syncthreads();
    }
    float mx = red[0];
    __syncthreads();
    float exv = 0.f;
    if (tid < 256) { exv = expf(e - mx); red[tid] = exv; }
    __syncthreads();
    for (int s = 128; s > 0; s >>= 1) {
        if (tid < s) red[tid] += red[tid + s];
        __syncthreads();
    }
    float winv = 1.f / red[0];
    __syncthreads();
    if (tid < 256) {
        float w = exv * winv;
        wgt_s[tid] = w;
        align_out[(size_t)b * 131072 + (size_t)t * 256 + tid] = w;
        awc[b * 256 + tid] = awc_s[tid] + w;
    }
    __syncthreads();

    // ctx[e] = sum_tt wgt[tt] * memory[b][tt][e]  (2-way tt split)
    {
        int ee = tid & 511, p = tid >> 9;
        const float* mr = memory + (size_t)b * 131072 + ee;
        float s = 0.f;
        for (int ttl = 0; ttl < 128; ++ttl) {
            int tt = p * 128 + ttl;
            s += wgt_s[tt] * mr[(size_t)tt * 512];
        }
        red[p * 512 + ee] = s;
    }
    __syncthreads();
    if (tid < 512) ctx[b * 512 + tid] = red[tid] + red[512 + tid];
}

// ============================================================
// Projection + gate
// ============================================================
__global__ __launch_bounds__(256) void proj_kernel(
    const float* __restrict__ dh,       // (32,1024)
    const float* __restrict__ ctx,      // (32,512)
    const float* __restrict__ proj_w,   // (80,1536)
    const float* __restrict__ proj_b,   // (80)
    const float* __restrict__ gate_w,   // (1536)
    const float* __restrict__ gate_b,   // (1)
    float* __restrict__ out_mel,        // (32,80,512)
    float* __restrict__ out_gate,       // (32,512)
    int t)
{
    int b = blockIdx.x, tid = threadIdx.x;
    __shared__ float pi[1536];
    __shared__ float red[256];
    for (int i = tid; i < 1024; i += 256) pi[i] = dh[b * 1024 + i];
    for (int i = tid; i < 512; i += 256) pi[1024 + i] = ctx[b * 512 + i];
    __syncthreads();

    float s = 0.f;
    if (tid < 240) {
        int m = tid / 3, p = tid - m * 3;
        const float* wr = proj_w + (size_t)m * 1536 + p * 512;
        const float* pr = pi + p * 512;
        for (int k = 0; k < 512; ++k) s += wr[k] * pr[k];
    } else {
        int p = tid - 240;
        const float* wr = gate_w + p * 96;
        const float* pr = pi + p * 96;
        for (int k = 0; k < 96; ++k) s += wr[k] * pr[k];
    }
    red[tid] = s;
    __syncthreads();
    if (tid < 80) {
        float m3 = red[tid * 3] + red[tid * 3 + 1] + red[tid * 3 + 2];
        out_mel[(size_t)b * (80 * 512) + (size_t)tid * 512 + t] = m3 + proj_b[tid];
    } else if (tid == 80) {
        float g = gate_b[0];
#pragma unroll
        for (int p = 0; p < 16; ++p) g += red[240 + p];
        out_gate[b * 512 + t] = g;
    }
}

// ============================================================
extern "C" void kernel_launch(void* const* d_in, const int* in_sizes, int n_in,
                              void* d_out, int out_size, void* d_ws, size_t ws_size,
                              hipStream_t stream)
{
    const float* memory   = (const float*)d_in[0];
    const float* dec_in   = (const float*)d_in[1];
    const int*   mlen     = (const int*)  d_in[2];
    const float* pw1      = (const float*)d_in[3];
    const float* pw2      = (const float*)d_in[4];
    const float* a_wih    = (const float*)d_in[5];
    const float* a_whh    = (const float*)d_in[6];
    const float* a_b      = (const float*)d_in[7];
    const float* wq       = (const float*)d_in[8];
    const float* wm       = (const float*)d_in[9];
    const float* v        = (const float*)d_in[10];
    const float* lconv    = (const float*)d_in[11];
    const float* ldense   = (const float*)d_in[12];
    const float* d_wih    = (const float*)d_in[13];
    const float* d_whh    = (const float*)d_in[14];
    const float* d_b      = (const float*)d_in[15];
    const float* proj_w   = (const float*)d_in[16];
    const float* proj_b   = (const float*)d_in[17];
    const float* gate_w   = (const float*)d_in[18];
    const float* gate_b   = (const float*)d_in[19];

    float* out  = (float*)d_out;
    float* wsf  = (float*)d_ws;

    float* x2   = wsf + OFF_X2;
    float* pm   = wsf + OFF_PM;
    float* ah   = wsf + OFF_AH;
    float* ac   = wsf + OFF_AC;
    float* dh   = wsf + OFF_DH;
    float* dc   = wsf + OFF_DC;
    float* ctx  = wsf + OFF_CTX;
    float* awc  = wsf + OFF_AWC;

    float* out_mel   = out + OUT_MEL;
    float* out_gate  = out + OUT_GATE;
    float* out_align = out + OUT_ALIGN;

    // zero recurrent state (ws is poisoned before every launch)
    hipMemsetAsync((char*)d_ws + OFF_AH * sizeof(float), 0,
                   (WS_TOTAL - OFF_AH) * sizeof(float), stream);

    prenet_kernel<<<1024, 256, 0, stream>>>(dec_in, pw1, pw2, x2);
    pm_kernel<<<dim3(16, 32), 128, 0, stream>>>(memory, wm, pm);

    for (int t = 0; t < T_OUTT; ++t) {
        const float* ah_in = ah + (t & 1) * 32768;
        float*       ah_out = ah + ((t + 1) & 1) * 32768;
        const float* dh_in = dh + (t & 1) * 32768;
        float*       dh_out = dh + ((t + 1) & 1) * 32768;

        // attention LSTM: input = [x2[t] (256) | ctx (512) | ah_in (1024)]
        lstm_kernel<<<256, 256, 0, stream>>>(
            x2 + (size_t)t * (32 * 256), 256, 256,
            ctx, 512, 512,
            ah_in, 1024,
            a_wih, 768, a_whh, a_b,
            ac, ah_out, 1792);

        attn_kernel<<<32, 1024, 0, stream>>>(
            memory, mlen, wq, v, lconv, ldense, pm, ah_out,
            ctx, awc, out_align, t);

        // decoder LSTM: input = [ah_out (1024) | ctx (512) | dh_in (1024)]
        lstm_kernel<<<256, 256, 0, stream>>>(
            ah_out, 1024, 1024,
            ctx, 512, 512,
            dh_in, 1024,
            d_wih, 1536, d_whh, d_b,
            dc, dh_out, 2560);

        proj_kernel<<<32, 256, 0, stream>>>(
            dh_out, ctx, proj_w, proj_b, gate_w, gate_b,
            out_mel, out_gate, t);
    }
}

// Round 2
// 44895.953 us; speedup vs baseline: 2.7388x; 2.7388x over previous
//
#include <hip/hip_runtime.h>
#include <hip/hip_bf16.h>
#include <math.h>

typedef __attribute__((ext_vector_type(8))) short bf16x8;
typedef __attribute__((ext_vector_type(4))) float f32x4;

// ---- workspace byte offsets ----
#define B_X2    0u            // 512*32*256 bf16  = 8388608
#define B_PM    8388608u      // 32*256*128 f32   = 4194304
#define B_WSA   12582912u     // 4096*1792 bf16   = 14680064
#define B_WSD   27262976u     // 4096*2560 bf16   = 20971520
#define B_AHB0  48234496u     // 32*1024 bf16 x2
#define B_AHB1  48300032u
#define B_DHB0  48365568u
#define B_DHB1  48431104u
#define B_CTXB  48496640u     // 32*512 bf16
#define B_AC    48529408u     // 32*1024 f32
#define B_DC    48660480u
#define B_AWC   48791552u     // 32*256 f32
#define B_ZERO_START 48234496u
#define B_ZERO_BYTES 589824u
#define B_AHF   48824320u     // 32*1024 f32
#define B_DHF   48955392u
#define B_CTXF  49086464u     // 32*512 f32

// ---- output offsets (floats) ----
#define OUT_MEL   0u
#define OUT_GATE  1310720u
#define OUT_ALIGN 1327104u

__device__ __forceinline__ float sigf(float x) { return 1.f / (1.f + expf(-x)); }
__device__ __forceinline__ float ftanh(float x) {
    float t = exp2f(x * 2.885390081777927f);
    return 1.f - 2.f * __builtin_amdgcn_rcpf(t + 1.f);
}

// ============================================================
// Prenet for all timesteps -> bf16 x2[t][b][256]
// ============================================================
__global__ __launch_bounds__(256) void prenet_kernel(
    const float* __restrict__ dec_in,   // (B, 80, 512)
    const float* __restrict__ w1,       // (256, 80)
    const float* __restrict__ w2,       // (256, 256)
    __hip_bfloat16* __restrict__ x2)    // (512, 32, 256) bf16
{
    int b  = blockIdx.x & 31;
    int t0 = (blockIdx.x >> 5) * 16;
    __shared__ float xin[16][80];
    __shared__ float h1[16][257];

    for (int i = threadIdx.x; i < 16 * 80; i += 256) {
        int tt = i / 80, m = i - tt * 80;
        int t = t0 + tt;
        xin[tt][m] = (t == 0) ? 0.f
                   : dec_in[(size_t)b * 80 * 512 + (size_t)m * 512 + (t - 1)];
    }
    __syncthreads();
    for (int i = threadIdx.x; i < 16 * 256; i += 256) {
        int tt = i >> 8, p = i & 255;
        const float* wr = w1 + p * 80;
        float s = 0.f;
        for (int m = 0; m < 80; ++m) s += xin[tt][m] * wr[m];
        h1[tt][p] = fmaxf(s, 0.f);
    }
    __syncthreads();
    for (int i = threadIdx.x; i < 16 * 256; i += 256) {
        int tt = i >> 8, q = i & 255;
        const float* wr = w2 + q * 256;
        float s = 0.f;
        for (int p = 0; p < 256; ++p) s += h1[tt][p] * wr[p];
        int t = t0 + tt;
        x2[(size_t)t * (32 * 256) + b * 256 + q] = __float2bfloat16(fmaxf(s, 0.f));
    }
}

// ============================================================
// processed_memory (f32)
// ============================================================
__global__ __launch_bounds__(128) void pm_kernel(
    const float* __restrict__ memory,   // (32, 256, 512)
    const float* __restrict__ wm,       // (128, 512)
    float* __restrict__ pm)             // (32, 256, 128)
{
    int b = blockIdx.y, tt0 = blockIdx.x * 16;
    __shared__ float ms[16][513];
    for (int i = threadIdx.x; i < 16 * 512; i += 128) {
        int tt = i >> 9, e = i & 511;
        ms[tt][e] = memory[(size_t)b * 131072 + (size_t)(tt0 + tt) * 512 + e];
    }
    __syncthreads();
    int d = threadIdx.x;
    float acc[16];
#pragma unroll
    for (int i = 0; i < 16; ++i) acc[i] = 0.f;
    const float* wr = wm + d * 512;
    for (int e = 0; e < 512; ++e) {
        float w = wr[e];
#pragma unroll
        for (int ttl = 0; ttl < 16; ++ttl) acc[ttl] += w * ms[ttl][e];
    }
    for (int ttl = 0; ttl < 16; ++ttl)
        pm[(size_t)b * 32768 + (size_t)(tt0 + ttl) * 128 + d] = acc[ttl];
}

// ============================================================
// Weight swizzle: rows n -> gate-interleaved tiles, bf16, B-frag layout
// out[((nt*KB + kb)*64 + lane)*8 + j]
//   n = (c>>2)*1024 + nt*4 + (c&3), c = lane&15; k = kb*32 + (lane>>4)*8 + j
// ============================================================
__global__ __launch_bounds__(256) void swizzle_kernel(
    const float* __restrict__ wih, int Kih,
    const float* __restrict__ whh, int Khh,
    __hip_bfloat16* __restrict__ out, int K)
{
    int idx = blockIdx.x * 256 + threadIdx.x;  // (nt*KB + kb)*64 + lane
    int lane = idx & 63;
    int tk = idx >> 6;
    int KB = K >> 5;
    int nt = tk / KB, kb = tk - nt * KB;
    int c = lane & 15;
    int n = (c >> 2) * 1024 + nt * 4 + (c & 3);
    int k = kb * 32 + ((lane >> 4) << 3);
    const float* src; int kk;
    if (k < Kih) { src = wih + (size_t)n * Kih; kk = k; }
    else         { src = whh + (size_t)n * Khh; kk = k - Kih; }
    __hip_bfloat16* op = out + (size_t)idx * 8;
#pragma unroll
    for (int j = 0; j < 8; ++j) op[j] = __float2bfloat16(src[kk + j]);
}

// ============================================================
// Fused bf16-MFMA LSTM: gates GEMM + pointwise epilogue
// grid 256 (n-tile of 4 j x 4 gates), 512 threads = 8 waves (8-way K-split)
// ============================================================
template<int K, int S0, int S1, int S0STR, int S1STR, int S2STR>
__global__ __launch_bounds__(512, 2) void lstm_gemm(
    const __hip_bfloat16* __restrict__ seg0,
    const __hip_bfloat16* __restrict__ seg1,
    const __hip_bfloat16* __restrict__ seg2,
    const __hip_bfloat16* __restrict__ wsw,
    const float* __restrict__ bias,
    float* __restrict__ c_state,
    float* __restrict__ h_f32,
    __hip_bfloat16* __restrict__ h_bf16)
{
    constexpr int KB  = K / 32;
    constexpr int NCH = K / 256;    // chunks per wave

    __shared__ float red[8][2][4][64];
    __shared__ float gsum[32][17];

    int nt   = blockIdx.x;
    int tid  = threadIdx.x;
    int lane = tid & 63;
    int w    = tid >> 6;
    int r0   = lane & 15;
    int kq   = (lane >> 4) << 3;

    const __hip_bfloat16* wp = wsw + (((size_t)nt * KB + (size_t)w * NCH) * 64 + lane) * 8;
    f32x4 acc0 = {0.f, 0.f, 0.f, 0.f};
    f32x4 acc1 = {0.f, 0.f, 0.f, 0.f};
    int k0 = w * (K / 8);

#pragma unroll
    for (int i = 0; i < NCH; ++i) {
        int kc = k0 + i * 32;
        const __hip_bfloat16* sp; int sstr, off;
        if (kc < S0)           { sp = seg0; sstr = S0STR; off = kc; }
        else if (kc < S0 + S1) { sp = seg1; sstr = S1STR; off = kc - S0; }
        else                   { sp = seg2; sstr = S2STR; off = kc - S0 - S1; }
        int ko = off + kq;
        bf16x8 a0 = *(const bf16x8*)(sp + (size_t)r0 * sstr + ko);
        bf16x8 a1 = *(const bf16x8*)(sp + (size_t)(r0 + 16) * sstr + ko);
        bf16x8 bb = *(const bf16x8*)(wp + (size_t)i * 512);
        acc0 = __builtin_amdgcn_mfma_f32_16x16x32_bf16(a0, bb, acc0, 0, 0, 0);
        acc1 = __builtin_amdgcn_mfma_f32_16x16x32_bf16(a1, bb, acc1, 0, 0, 0);
    }

#pragma unroll
    for (int r = 0; r < 4; ++r) {
        red[w][0][r][lane] = acc0[r];
        red[w][1][r][lane] = acc1[r];
    }
    __syncthreads();

    // 8-way reduce: thread t -> (b = t>>4, c = t&15)
    {
        int b = tid >> 4, c = tid & 15;
        int mt = b >> 4, bm = b & 15;
        int lidx = ((bm >> 2) << 4) + c, rg = bm & 3;
        float s = 0.f;
#pragma unroll
        for (int ks = 0; ks < 8; ++ks) s += red[ks][mt][rg][lidx];
        gsum[b][c] = s;
    }
    __syncthreads();

    if (tid < 128) {
        int b = tid & 31, jl = tid >> 5;
        int j = nt * 4 + jl;
        float gi = gsum[b][jl]      + bias[j];
        float gf = gsum[b][4 + jl]  + bias[1024 + j];
        float gg = gsum[b][8 + jl]  + bias[2048 + j];
        float go = gsum[b][12 + jl] + bias[3072 + j];
        float cv = c_state[b * 1024 + j];
        float c2 = sigf(gf) * cv + sigf(gi) * tanhf(gg);
        float h2 = sigf(go) * tanhf(c2);
        c_state[b * 1024 + j] = c2;
        h_f32[b * 1024 + j]   = h2;
        h_bf16[b * 1024 + j]  = __float2bfloat16(h2);
    }
}

// ============================================================
// Attention: 32 blocks x 1024 threads; MFMA for loc->A_DIM dense
// ============================================================
__global__ __launch_bounds__(1024) void attn_kernel(
    const float* __restrict__ memory,     // (32,256,512)
    const int*   __restrict__ mlen,
    const float* __restrict__ wq,         // (128,1024)
    const float* __restrict__ v,          // (128)
    const float* __restrict__ loc_conv,   // (32,2,31)
    const float* __restrict__ loc_dense,  // (128,32)
    const float* __restrict__ pm,         // (32,256,128)
    const float* __restrict__ ah,         // (32,1024) f32
    float* __restrict__ ctx,              // (32,512) f32
    __hip_bfloat16* __restrict__ ctx_bf,  // (32,512) bf16
    float* __restrict__ awc,              // (32,256)
    float* __restrict__ align_out,        // (32,512,256)
    int t)
{
    int b = blockIdx.x, tid = threadIdx.x;
    __shared__ float aw_s[288];
    __shared__ float awc_s[288];
    __shared__ __hip_bfloat16 locb[256][40];
    __shared__ float pq_s[128];
    __shared__ float red[1024];
    __shared__ float esh[256];
    __shared__ float wgt_s[256];

    int len = mlen[b];

    // ---- phase A: stage aw/awc (zero-padded window) + pq partials ----
    for (int i = tid; i < 288; i += 1024) {
        int tt = i - 15;
        float a = 0.f, c = 0.f;
        if (tt >= 0 && tt < 256) {
            a = (t == 0) ? 0.f
              : align_out[(size_t)b * 131072 + (size_t)(t - 1) * 256 + tt];
            c = awc[b * 256 + tt];
        }
        aw_s[i] = a; awc_s[i] = c;
    }
    {
        int d = tid >> 3, p = tid & 7;
        const float4* wr = (const float4*)(wq + (size_t)d * 1024 + p * 128);
        const float4* hr = (const float4*)(ah + b * 1024 + p * 128);
        float s = 0.f;
#pragma unroll 8
        for (int k = 0; k < 32; ++k) {
            float4 a = wr[k], h4 = hr[k];
            s += a.x * h4.x + a.y * h4.y + a.z * h4.z + a.w * h4.w;
        }
        red[tid] = s;
    }
    __syncthreads();

    // ---- phase B: pq reduce + location conv (register sliding) ----
    if (tid < 128) {
        float s = 0.f;
#pragma unroll
        for (int p = 0; p < 8; ++p) s += red[tid * 8 + p];
        pq_s[tid] = s;
    }
    {
        int f = tid >> 5, ttg = tid & 31;
        const float* kcA = loc_conv + f * 62;
        const float* kcB = kcA + 31;
        float ka[31], kb_[31];
#pragma unroll
        for (int k = 0; k < 31; ++k) { ka[k] = kcA[k]; kb_[k] = kcB[k]; }
        float acc[8];
#pragma unroll
        for (int s = 0; s < 8; ++s) acc[s] = 0.f;
        int base = ttg * 8;
#pragma unroll
        for (int u = 0; u < 38; ++u) {
            float av = aw_s[base + u];
            float cv = awc_s[base + u];
#pragma unroll
            for (int s = 0; s < 8; ++s) {
                int k = u - s;
                if (k >= 0 && k < 31) {
                    acc[s] = fmaf(ka[k], av, acc[s]);
                    acc[s] = fmaf(kb_[k], cv, acc[s]);
                }
            }
        }
#pragma unroll
        for (int s = 0; s < 8; ++s)
            locb[base + s][f] = __float2bfloat16(acc[s]);
    }
    __syncthreads();

    // ---- phase C: energies via MFMA (M=tt 16/wave, N=d 128, K=f 32) ----
    {
        int lane = tid & 63;
        int w16  = tid >> 6;          // tile row (tt group)
        int c    = lane & 15, q = lane >> 4;

        bf16x8 Bf[8];
#pragma unroll
        for (int tc = 0; tc < 8; ++tc) {
            int d = tc * 16 + c;
            const float* lp = loc_dense + d * 32 + q * 8;
            float4 f0 = *(const float4*)lp;
            float4 f1 = *(const float4*)(lp + 4);
            union { bf16x8 vv; __hip_bfloat16 h[8]; } u;
            u.h[0] = __float2bfloat16(f0.x); u.h[1] = __float2bfloat16(f0.y);
            u.h[2] = __float2bfloat16(f0.z); u.h[3] = __float2bfloat16(f0.w);
            u.h[4] = __float2bfloat16(f1.x); u.h[5] = __float2bfloat16(f1.y);
            u.h[6] = __float2bfloat16(f1.z); u.h[7] = __float2bfloat16(f1.w);
            Bf[tc] = u.vv;
        }
        bf16x8 Af = *(const bf16x8*)&locb[w16 * 16 + c][q * 8];

        f32x4 zero = {0.f, 0.f, 0.f, 0.f};
        float se[4] = {0.f, 0.f, 0.f, 0.f};
#pragma unroll
        for (int tc = 0; tc < 8; ++tc) {
            f32x4 P = __builtin_amdgcn_mfma_f32_16x16x32_bf16(Af, Bf[tc], zero, 0, 0, 0);
            int d = tc * 16 + c;
            float vv = v[d];
            float pqv = pq_s[d];
#pragma unroll
            for (int r = 0; r < 4; ++r) {
                int ttp = w16 * 16 + q * 4 + r;
                float x = P[r] + pqv + pm[((size_t)b << 15) + ttp * 128 + d];
                se[r] = fmaf(ftanh(x), vv, se[r]);
            }
        }
#pragma unroll
        for (int m = 1; m < 16; m <<= 1) {
#pragma unroll
            for (int r = 0; r < 4; ++r) se[r] += __shfl_xor(se[r], m);
        }
        if (c == 0) {
#pragma unroll
            for (int r = 0; r < 4; ++r) esh[w16 * 16 + q * 4 + r] = se[r];
        }
    }
    __syncthreads();

    // ---- phase D: softmax + align/awc writes ----
    float e = 0.f;
    if (tid < 256) {
        e = (tid < len) ? esh[tid] : -1e9f;
        red[tid] = e;
    }
    __syncthreads();
    for (int s = 128; s > 0; s >>= 1) {
        if (tid < s) red[tid] = fmaxf(red[tid], red[tid + s]);
        __syncthreads();
    }
    float mx = red[0];
    __syncthreads();
    float exv = 0.f;
    if (tid < 256) {
        exv = exp2f((e - mx) * 1.4426950408889634f);
        red[tid] = exv;
    }
    __syncthreads();
    for (int s = 128; s > 0; s >>= 1) {
        if (tid < s) red[tid] += red[tid + s];
        __syncthreads();
    }
    float winv = __builtin_amdgcn_rcpf(red[0]);
    __syncthreads();
    if (tid < 256) {
        float wg = exv * winv;
        wgt_s[tid] = wg;
        align_out[(size_t)b * 131072 + (size_t)t * 256 + tid] = wg;
        awc[b * 256 + tid] = awc_s[tid + 15] + wg;
    }
    __syncthreads();

    // ---- phase E: context ----
    {
        int ee = tid & 511, p = tid >> 9;
        const float* mr = memory + (size_t)b * 131072 + ee;
        float s = 0.f;
        for (int ttl = 0; ttl < 128; ++ttl) {
            int tt = p * 128 + ttl;
            s = fmaf(wgt_s[tt], mr[(size_t)tt * 512], s);
        }
        red[p * 512 + ee] = s;
    }
    __syncthreads();
    if (tid < 512) {
        float cv = red[tid] + red[512 + tid];
        ctx[b * 512 + tid] = cv;
        ctx_bf[b * 512 + tid] = __float2bfloat16(cv);
    }
}

// ============================================================
// Projection + gate (f32)
// ============================================================
__global__ __launch_bounds__(256) void proj_kernel(
    const float* __restrict__ dh,       // (32,1024)
    const float* __restrict__ ctx,      // (32,512)
    const float* __restrict__ proj_w,   // (80,1536)
    const float* __restrict__ proj_b,   // (80)
    const float* __restrict__ gate_w,   // (1536)
    const float* __restrict__ gate_b,   // (1)
    float* __restrict__ out_mel,        // (32,80,512)
    float* __restrict__ out_gate,       // (32,512)
    int t)
{
    int b = blockIdx.x, tid = threadIdx.x;
    __shared__ float pi[1536];
    __shared__ float red[256];
    for (int i = tid; i < 1024; i += 256) pi[i] = dh[b * 1024 + i];
    for (int i = tid; i < 512; i += 256) pi[1024 + i] = ctx[b * 512 + i];
    __syncthreads();

    float s = 0.f;
    if (tid < 240) {
        int m = tid / 3, p = tid - m * 3;
        const float* wr = proj_w + (size_t)m * 1536 + p * 512;
        const float* pr = pi + p * 512;
        for (int k = 0; k < 512; ++k) s += wr[k] * pr[k];
    } else {
        int p = tid - 240;
        const float* wr = gate_w + p * 96;
        const float* pr = pi + p * 96;
        for (int k = 0; k < 96; ++k) s += wr[k] * pr[k];
    }
    red[tid] = s;
    __syncthreads();
    if (tid < 80) {
        float m3 = red[tid * 3] + red[tid * 3 + 1] + red[tid * 3 + 2];
        out_mel[(size_t)b * (80 * 512) + (size_t)tid * 512 + t] = m3 + proj_b[tid];
    } else if (tid == 80) {
        float g = gate_b[0];
#pragma unroll
        for (int p = 0; p < 16; ++p) g += red[240 + p];
        out_gate[b * 512 + t] = g;
    }
}

// ============================================================
extern "C" void kernel_launch(void* const* d_in, const int* in_sizes, int n_in,
                              void* d_out, int out_size, void* d_ws, size_t ws_size,
                              hipStream_t stream)
{
    const float* memory   = (const float*)d_in[0];
    const float* dec_in   = (const float*)d_in[1];
    const int*   mlen     = (const int*)  d_in[2];
    const float* pw1      = (const float*)d_in[3];
    const float* pw2      = (const float*)d_in[4];
    const float* a_wih    = (const float*)d_in[5];
    const float* a_whh    = (const float*)d_in[6];
    const float* a_b      = (const float*)d_in[7];
    const float* wq       = (const float*)d_in[8];
    const float* wm       = (const float*)d_in[9];
    const float* v        = (const float*)d_in[10];
    const float* lconv    = (const float*)d_in[11];
    const float* ldense   = (const float*)d_in[12];
    const float* d_wih    = (const float*)d_in[13];
    const float* d_whh    = (const float*)d_in[14];
    const float* d_b      = (const float*)d_in[15];
    const float* proj_w   = (const float*)d_in[16];
    const float* proj_b   = (const float*)d_in[17];
    const float* gate_w   = (const float*)d_in[18];
    const float* gate_b   = (const float*)d_in[19];

    char* ws = (char*)d_ws;
    __hip_bfloat16* x2b  = (__hip_bfloat16*)(ws + B_X2);
    float*          pm   = (float*)(ws + B_PM);
    __hip_bfloat16* wswA = (__hip_bfloat16*)(ws + B_WSA);
    __hip_bfloat16* wswD = (__hip_bfloat16*)(ws + B_WSD);
    __hip_bfloat16* ahb0 = (__hip_bfloat16*)(ws + B_AHB0);
    __hip_bfloat16* ahb1 = (__hip_bfloat16*)(ws + B_AHB1);
    __hip_bfloat16* dhb0 = (__hip_bfloat16*)(ws + B_DHB0);
    __hip_bfloat16* dhb1 = (__hip_bfloat16*)(ws + B_DHB1);
    __hip_bfloat16* ctxb = (__hip_bfloat16*)(ws + B_CTXB);
    float*          ac   = (float*)(ws + B_AC);
    float*          dc   = (float*)(ws + B_DC);
    float*          awcp = (float*)(ws + B_AWC);
    float*          ahf  = (float*)(ws + B_AHF);
    float*          dhf  = (float*)(ws + B_DHF);
    float*          ctxf = (float*)(ws + B_CTXF);

    float* out       = (float*)d_out;
    float* out_mel   = out + OUT_MEL;
    float* out_gate  = out + OUT_GATE;
    float* out_align = out + OUT_ALIGN;

    hipMemsetAsync(ws + B_ZERO_START, 0, B_ZERO_BYTES, stream);

    prenet_kernel<<<1024, 256, 0, stream>>>(dec_in, pw1, pw2, x2b);
    pm_kernel<<<dim3(16, 32), 128, 0, stream>>>(memory, wm, pm);
    swizzle_kernel<<<3584, 256, 0, stream>>>(a_wih, 768,  a_whh, 1024, wswA, 1792);
    swizzle_kernel<<<5120, 256, 0, stream>>>(d_wih, 1536, d_whh, 1024, wswD, 2560);

    for (int t = 0; t < 512; ++t) {
        __hip_bfloat16* ah_prev = (t & 1) ? ahb1 : ahb0;
        __hip_bfloat16* ah_cur  = (t & 1) ? ahb0 : ahb1;
        __hip_bfloat16* dh_prev = (t & 1) ? dhb1 : dhb0;
        __hip_bfloat16* dh_cur  = (t & 1) ? dhb0 : dhb1;

        // attention LSTM: [x2[t] (256) | ctx (512) | ah_prev (1024)]
        lstm_gemm<1792, 256, 512, 256, 512, 1024><<<256, 512, 0, stream>>>(
            x2b + (size_t)t * 8192, ctxb, ah_prev,
            wswA, a_b, ac, ahf, ah_cur);

        attn_kernel<<<32, 1024, 0, stream>>>(
            memory, mlen, wq, v, lconv, ldense, pm, ahf,
            ctxf, ctxb, awcp, out_align, t);

        // decoder LSTM: [ah_cur (1024) | ctx (512) | dh_prev (1024)]
        lstm_gemm<2560, 1024, 512, 1024, 512, 1024><<<256, 512, 0, stream>>>(
            ah_cur, ctxb, dh_prev,
            wswD, d_b, dc, dhf, dh_cur);

        proj_kernel<<<32, 256, 0, stream>>>(
            dhf, ctxf, proj_w, proj_b, gate_w, gate_b,
            out_mel, out_gate, t);
    }
}